// Round 5
// baseline (769.095 us; speedup 1.0000x reference)
//
#include <hip/hip_runtime.h>
#include <math.h>

// Problem constants (fixed by reference)
#define N_NODES 50000
#define N_FEAT  500
#define DH      256
#define KC      16
#define NE      800000
#define KPAD    512     // N_FEAT padded to MFMA K multiple
#define MPAD    50048   // 391 * 128 (GEMM M tiles)
#define M2      (2 * MPAD)
#define SPMM_BLOCKS 2048

typedef __attribute__((ext_vector_type(8))) short short8;
typedef __attribute__((ext_vector_type(4))) float f32x4;

__device__ __forceinline__ unsigned short f2bf(float f) {
  unsigned u = __float_as_uint(f);
  u += 0x7FFFu + ((u >> 16) & 1u);   // RNE
  return (unsigned short)(u >> 16);
}

__device__ __forceinline__ float bf2f(unsigned short u) {
  return __uint_as_float((unsigned)u << 16);
}

__device__ __forceinline__ float selu_f(float x) {
  return 1.0507009873554805f * (x > 0.f ? x : 1.6732632423543772f * expm1f(x));
}

__device__ __forceinline__ void gload16(const void* g, void* l) {
  __builtin_amdgcn_global_load_lds(
      (const __attribute__((address_space(1))) unsigned int*)g,
      (__attribute__((address_space(3))) unsigned int*)l, 16, 0, 0);
}

// ---- f32 -> bf16 with zero padding (used only for W1) ----
__global__ void k_cvt_pad(const float* __restrict__ in, unsigned short* __restrict__ out,
                          int rin, int cin, int rout, int cout) {
  const int cquads = cout >> 2;
  const long total = (long)rout * cquads;
  for (long idx = (long)blockIdx.x * blockDim.x + threadIdx.x; idx < total;
       idx += (long)gridDim.x * blockDim.x) {
    const int row = (int)(idx / cquads);
    const int c4  = (int)(idx - (long)row * cquads) * 4;
    float x = 0.f, y = 0.f, z = 0.f, w = 0.f;
    if (row < rin && c4 < cin) {
      const float4 v = *(const float4*)(in + (size_t)row * cin + c4);
      x = v.x; y = v.y; z = v.z; w = v.w;
    }
    ushort4 o; o.x = f2bf(x); o.y = f2bf(y); o.z = f2bf(z); o.w = f2bf(w);
    *(ushort4*)(out + (size_t)row * cout + c4) = o;
  }
}

// ---- Fused f32->bf16 GEMM: C[m][n] = sum_k A[m][k]*W[n][k]
//      A = features (rows [0,MPAD)) or aug (rows [MPAD,2*MPAD)), f32 [N][500]
//      W = Wbf bf16 [256][512]; tile 128x256, 512 threads, 8 waves of 64x64. ----
__global__ __launch_bounds__(512, 2) void k_gemm_fused(
    const float* __restrict__ Af, const float* __restrict__ Aa,
    const unsigned short* __restrict__ Wbf, unsigned short* __restrict__ C) {
  __shared__ short As[128 * 64];
  __shared__ short Bs[256 * 64];
  const int t = threadIdx.x;
  const int lane = t & 63, wave = t >> 6;
  const int wr = (wave >> 2) * 64, wc = (wave & 3) * 64;
  const int bm = blockIdx.x * 128;
  const bool isaug = bm >= MPAD;
  const float* __restrict__ src = isaug ? Aa : Af;
  const int row0 = isaug ? bm - MPAD : bm;
  const int lr = lane & 15, lk = (lane >> 4) * 8;
  const int ar = t >> 3, ac = (t & 7) * 8;
  f32x4 acc[4][4] = {};
  for (int kb = 0; kb < KPAD; kb += 64) {
#pragma unroll
    for (int i = 0; i < 4; ++i) {
      const int chunk = i * 512 + t;
      const int rb = chunk >> 3, sub = (chunk & 7) * 8;
      gload16(Wbf + (size_t)rb * KPAD + kb + sub, (void*)(Bs + (size_t)chunk * 8));
    }
#pragma unroll
    for (int h = 0; h < 128; h += 64) {
      const int gr = row0 + ar + h;
      const int c = kb + ac;
      const bool vr = gr < N_NODES;
      float4 u0 = {0.f, 0.f, 0.f, 0.f}, u1 = {0.f, 0.f, 0.f, 0.f};
      const float* arow = src + (size_t)gr * N_FEAT;
      if (vr && c < N_FEAT)     u0 = *(const float4*)(arow + c);
      if (vr && c + 4 < N_FEAT) u1 = *(const float4*)(arow + c + 4);
      short8 w;
      w[0] = (short)f2bf(u0.x); w[1] = (short)f2bf(u0.y);
      w[2] = (short)f2bf(u0.z); w[3] = (short)f2bf(u0.w);
      w[4] = (short)f2bf(u1.x); w[5] = (short)f2bf(u1.y);
      w[6] = (short)f2bf(u1.z); w[7] = (short)f2bf(u1.w);
      *(short8*)(As + (size_t)(ar + h) * 64 + ac) = w;
    }
    __syncthreads();
#pragma unroll
    for (int kk = 0; kk < 64; kk += 32) {
      short8 af[4], bfr[4];
#pragma unroll
      for (int m = 0; m < 4; ++m)
        af[m] = *(const short8*)(As + (wr + m * 16 + lr) * 64 + kk + lk);
#pragma unroll
      for (int n = 0; n < 4; ++n)
        bfr[n] = *(const short8*)(Bs + (wc + n * 16 + lr) * 64 + kk + lk);
#pragma unroll
      for (int m = 0; m < 4; ++m)
#pragma unroll
        for (int n = 0; n < 4; ++n)
          acc[m][n] = __builtin_amdgcn_mfma_f32_16x16x32_bf16(af[m], bfr[n], acc[m][n], 0, 0, 0);
    }
    __syncthreads();
  }
  const int crow = (lane >> 4) * 4, ccol = lane & 15;
#pragma unroll
  for (int m = 0; m < 4; ++m)
#pragma unroll
    for (int n = 0; n < 4; ++n)
#pragma unroll
      for (int r = 0; r < 4; ++r)
        C[(size_t)(bm + wr + m * 16 + crow + r) * DH + (wc + n * 16 + ccol)] =
            f2bf(acc[m][n][r]);
}

// ---- CSR build ----
__global__ void k_count(const int* __restrict__ row, int* __restrict__ counts) {
  const int e = blockIdx.x * blockDim.x + threadIdx.x;
  if (e < NE) atomicAdd(&counts[row[e]], 1);
}

__global__ __launch_bounds__(1024) void k_scan(const int* __restrict__ counts,
                                               int* __restrict__ row_ptr, int* __restrict__ cursor) {
  __shared__ int part[1024];
  const int t = threadIdx.x;
  const int per = (N_NODES + 1023) / 1024;
  const int base = t * per;
  int s = 0;
  for (int i = 0; i < per; ++i) { const int j = base + i; if (j < N_NODES) s += counts[j]; }
  part[t] = s;
  __syncthreads();
  for (int off = 1; off < 1024; off <<= 1) {
    const int v = (t >= off) ? part[t - off] : 0;
    __syncthreads();
    part[t] += v;
    __syncthreads();
  }
  int run = (t == 0) ? 0 : part[t - 1];
  for (int i = 0; i < per; ++i) {
    const int j = base + i;
    if (j < N_NODES) { row_ptr[j] = run; cursor[j] = run; run += counts[j]; }
  }
  if (t == 1023) row_ptr[N_NODES] = part[1023];
}

__global__ void k_scatter(const int* __restrict__ row, const int* __restrict__ col,
                          const float* __restrict__ gnv, int* __restrict__ cursor,
                          int* __restrict__ ecol, float* __restrict__ eval) {
  const int e = blockIdx.x * blockDim.x + threadIdx.x;
  if (e < NE) {
    const int p = atomicAdd(&cursor[row[e]], 1);
    ecol[p] = col[e];
    eval[p] = gnv[e];
  }
}

// ---- Persistent combined SpMM (features + aug) + full fused epilogue.
//      2048 blocks, one wave per row, grid-stride over rows (~6 rows/wave).
//      Half-wave covers a 512B bf16 row (lane: 8 cols). Straightline gathers
//      (8 edges/iter, compiler-scheduled). exp/aug/dot/cs accumulate in
//      REGISTERS across rows; one LDS+global flush per block. ----
__global__ __launch_bounds__(256, 4) void k_spmm_fused(
    const int* __restrict__ row_ptr, const int* __restrict__ ecol, const float* __restrict__ eval,
    const unsigned short* __restrict__ XWf, const unsigned short* __restrict__ XWa,
    const float* __restrict__ b1, const float* __restrict__ Wt, const float* __restrict__ bt,
    float* __restrict__ S, float* __restrict__ exptot, float* __restrict__ augtot,
    float* __restrict__ csg, float* __restrict__ dotAG) {
  __shared__ float Wl[KC * DH];
  __shared__ float btl[KC];
  __shared__ float expacc[DH];
  __shared__ float augacc[DH];
  __shared__ float csacc[KC];
  __shared__ float dacc;
  for (int i4 = threadIdx.x; i4 < KC * DH / 4; i4 += 256)
    ((float4*)Wl)[i4] = ((const float4*)Wt)[i4];
  if (threadIdx.x < KC) { btl[threadIdx.x] = bt[threadIdx.x]; csacc[threadIdx.x] = 0.f; }
  expacc[threadIdx.x] = 0.f;
  augacc[threadIdx.x] = 0.f;
  if (threadIdx.x == 0) dacc = 0.f;
  __syncthreads();

  const int wave = threadIdx.x >> 6, lane = threadIdx.x & 63;
  const int half = lane >> 5;
  const int c0   = (lane & 31) * 8;
  const unsigned short* XF = XWf + c0;
  const unsigned short* XA = XWa + c0;
  const float4 blo = *(const float4*)(b1 + c0);
  const float4 bhi = *(const float4*)(b1 + c0 + 4);

  float lexp[8] = {0.f, 0.f, 0.f, 0.f, 0.f, 0.f, 0.f, 0.f};
  float laug[8] = {0.f, 0.f, 0.f, 0.f, 0.f, 0.f, 0.f, 0.f};
  float ldot = 0.f, lcs = 0.f;

  for (int i = blockIdx.x * 4 + wave; i < N_NODES; i += SPMM_BLOCKS * 4) {
    const int s = row_ptr[i], e = row_ptr[i + 1];
    float accf[8] = {0.f, 0.f, 0.f, 0.f, 0.f, 0.f, 0.f, 0.f};
    float acca[8] = {0.f, 0.f, 0.f, 0.f, 0.f, 0.f, 0.f, 0.f};
    for (int pb = s; pb < e; pb += 8) {
      int ci[4]; float vi[4];
#pragma unroll
      for (int j = 0; j < 4; ++j) {
        const int q = pb + 2 * j + half;
        const bool act = q < e;
        const int qi = act ? q : s;
        ci[j] = ecol[qi];
        vi[j] = act ? eval[qi] : 0.f;
      }
      short8 xf[4], xa[4];
#pragma unroll
      for (int j = 0; j < 4; ++j) {
        xf[j] = *(const short8*)(XF + (size_t)ci[j] * DH);
        xa[j] = *(const short8*)(XA + (size_t)ci[j] * DH);
      }
#pragma unroll
      for (int j = 0; j < 4; ++j)
#pragma unroll
        for (int u = 0; u < 8; ++u) {
          accf[u] += vi[j] * bf2f((unsigned short)xf[j][u]);
          acca[u] += vi[j] * bf2f((unsigned short)xa[j][u]);
        }
    }
    // fold the two halves (both get full row sums)
#pragma unroll
    for (int u = 0; u < 8; ++u) {
      accf[u] += __shfl_xor(accf[u], 32);
      acca[u] += __shfl_xor(acca[u], 32);
    }

    // bias + selu
    float of[8], oa[8];
    of[0] = selu_f(accf[0] + blo.x); of[1] = selu_f(accf[1] + blo.y);
    of[2] = selu_f(accf[2] + blo.z); of[3] = selu_f(accf[3] + blo.w);
    of[4] = selu_f(accf[4] + bhi.x); of[5] = selu_f(accf[5] + bhi.y);
    of[6] = selu_f(accf[6] + bhi.z); of[7] = selu_f(accf[7] + bhi.w);
    oa[0] = selu_f(acca[0] + blo.x); oa[1] = selu_f(acca[1] + blo.y);
    oa[2] = selu_f(acca[2] + blo.z); oa[3] = selu_f(acca[3] + blo.w);
    oa[4] = selu_f(acca[4] + bhi.x); oa[5] = selu_f(acca[5] + bhi.y);
    oa[6] = selu_f(acca[6] + bhi.z); oa[7] = selu_f(acca[7] + bhi.w);

    // register accumulation across rows (halves duplicate; flushed from half 0)
#pragma unroll
    for (int u = 0; u < 8; ++u) {
      lexp[u] += expf(of[u]);
      laug[u] += oa[u];
      ldot += oa[u] * of[u];
    }

    // assignments = softmax(of @ Wt^T + bt)
    float lg[KC];
#pragma unroll
    for (int k = 0; k < KC; ++k) {
      const float4 wlo = *(const float4*)(Wl + k * DH + c0);
      const float4 whi = *(const float4*)(Wl + k * DH + c0 + 4);
      lg[k] = of[0] * wlo.x + of[1] * wlo.y + of[2] * wlo.z + of[3] * wlo.w
            + of[4] * whi.x + of[5] * whi.y + of[6] * whi.z + of[7] * whi.w;
    }
#pragma unroll
    for (int off = 16; off; off >>= 1)
#pragma unroll
      for (int k = 0; k < KC; ++k) lg[k] += __shfl_xor(lg[k], off);
    float mx = -3.4e38f;
#pragma unroll
    for (int k = 0; k < KC; ++k) { lg[k] += btl[k]; mx = fmaxf(mx, lg[k]); }
    float se = 0.f;
#pragma unroll
    for (int k = 0; k < KC; ++k) { lg[k] = expf(lg[k] - mx); se += lg[k]; }
    const float inv = 1.f / se;
    float myv = 0.f;
#pragma unroll
    for (int k = 0; k < KC; ++k) if (lane == k) myv = lg[k];
    if (lane < KC) {
      const float sv = myv * inv;
      S[(size_t)i * KC + lane] = sv;
      lcs += sv;
    }
  }

  // ---- block-level flush ----
  // dot: reduce within half (each half holds full-row copies; use half 0's lane 0)
#pragma unroll
  for (int off = 16; off; off >>= 1) ldot += __shfl_xor(ldot, off);
  if (lane == 0) atomicAdd(&dacc, ldot);
  if (half == 0) {
#pragma unroll
    for (int u = 0; u < 8; ++u) {
      atomicAdd(&expacc[c0 + u], lexp[u]);
      atomicAdd(&augacc[c0 + u], laug[u]);
    }
  }
  if (lane < KC) atomicAdd(&csacc[lane], lcs);
  __syncthreads();
  atomicAdd(&exptot[threadIdx.x], expacc[threadIdx.x]);
  atomicAdd(&augtot[threadIdx.x], augacc[threadIdx.x]);
  if (threadIdx.x < KC) atomicAdd(&csg[threadIdx.x], csacc[threadIdx.x]);
  if (threadIdx.x == 0) atomicAdd(dotAG, dacc);
}

// ---- edge stats: tp = sum_e v*dot16(S[row],S[col]); nl[k] = sum_e v*S[col,k] ----
__global__ __launch_bounds__(256) void k_edge(const int* __restrict__ grow, const int* __restrict__ gcol,
                                              const float* __restrict__ gvals, const float* __restrict__ S,
                                              float* __restrict__ nl, float* __restrict__ tp) {
  float ltp = 0.f;
  float lnl[KC];
#pragma unroll
  for (int k = 0; k < KC; ++k) lnl[k] = 0.f;
  for (long e = (long)blockIdx.x * 256 + threadIdx.x; e < NE; e += (long)gridDim.x * 256) {
    const int r = grow[e], c = gcol[e];
    const float v = gvals[e];
    const float4* sr = (const float4*)(S + (size_t)r * KC);
    const float4* sc = (const float4*)(S + (size_t)c * KC);
    const float4 a0 = sr[0], a1 = sr[1], a2 = sr[2], a3 = sr[3];
    const float4 b0 = sc[0], b1v = sc[1], b2 = sc[2], b3 = sc[3];
    const float dot = a0.x * b0.x + a0.y * b0.y + a0.z * b0.z + a0.w * b0.w
                    + a1.x * b1v.x + a1.y * b1v.y + a1.z * b1v.z + a1.w * b1v.w
                    + a2.x * b2.x + a2.y * b2.y + a2.z * b2.z + a2.w * b2.w
                    + a3.x * b3.x + a3.y * b3.y + a3.z * b3.z + a3.w * b3.w;
    ltp += v * dot;
    lnl[0] += v * b0.x;  lnl[1] += v * b0.y;  lnl[2] += v * b0.z;  lnl[3] += v * b0.w;
    lnl[4] += v * b1v.x; lnl[5] += v * b1v.y; lnl[6] += v * b1v.z; lnl[7] += v * b1v.w;
    lnl[8] += v * b2.x;  lnl[9] += v * b2.y;  lnl[10] += v * b2.z; lnl[11] += v * b2.w;
    lnl[12] += v * b3.x; lnl[13] += v * b3.y; lnl[14] += v * b3.z; lnl[15] += v * b3.w;
  }
#pragma unroll
  for (int off = 32; off; off >>= 1) {
    ltp += __shfl_xor(ltp, off);
#pragma unroll
    for (int k = 0; k < KC; ++k) lnl[k] += __shfl_xor(lnl[k], off);
  }
  __shared__ float wred[4][KC + 1];
  const int wave = threadIdx.x >> 6, lane = threadIdx.x & 63;
  if (lane == 0) {
    wred[wave][0] = ltp;
#pragma unroll
    for (int k = 0; k < KC; ++k) wred[wave][1 + k] = lnl[k];
  }
  __syncthreads();
  if (threadIdx.x < KC + 1) {
    const float s = wred[0][threadIdx.x] + wred[1][threadIdx.x] + wred[2][threadIdx.x] + wred[3][threadIdx.x];
    if (threadIdx.x == 0) atomicAdd(tp, s);
    else atomicAdd(&nl[threadIdx.x - 1], s);
  }
}

// ---- final scalar assembly ----
// scal layout: [0]=dotAG, [1]=tp, [2..17]=nl, [18..33]=cs
__global__ void k_final(const float* __restrict__ exptot, const float* __restrict__ augtot,
                        const float* __restrict__ scal, float* __restrict__ out) {
  const int d = threadIdx.x;
  const float L = logf(exptot[d]);
  const float sa = augtot[d];
  __shared__ float red[DH];
  red[d] = L * sa;
  __syncthreads();
  for (int off = 128; off; off >>= 1) {
    if (d < off) red[d] += red[d + off];
    __syncthreads();
  }
  if (d == 0) {
    const float sumLA = red[0];
    const float dotAG = scal[0];
    const float tp = scal[1];
    float nl2 = 0.f, cs2 = 0.f;
#pragma unroll
    for (int k = 0; k < KC; ++k) {
      nl2 += scal[2 + k] * scal[2 + k];
      cs2 += scal[18 + k] * scal[18 + k];
    }
    const float fE = (float)NE;
    const float con = -(dotAG - sumLA) / (float)DH;
    const float trn = nl2 / (2.f * fE);
    const float spectral = -(tp - trn) / (2.f * fE);
    const float cluster = (sqrtf(cs2) / (float)N_NODES * 4.f - 1.f);
    out[0] = spectral + cluster + 0.5f * con;
  }
}

extern "C" void kernel_launch(void* const* d_in, const int* in_sizes, int n_in,
                              void* d_out, int out_size, void* d_ws, size_t ws_size,
                              hipStream_t stream) {
  const float* features = (const float*)d_in[0];
  const float* augf     = (const float*)d_in[1];
  const int*   grow     = (const int*)d_in[2];
  const int*   gcol     = (const int*)d_in[3];
  const float* gvals    = (const float*)d_in[4];
  const float* gnv      = (const float*)d_in[5];
  const float* W1       = (const float*)d_in[8];
  const float* b1       = (const float*)d_in[9];
  const float* Wt       = (const float*)d_in[10];
  const float* bt       = (const float*)d_in[11];

  char* ws = (char*)d_ws;
  size_t off = 0;
  auto alloc = [&](size_t bytes) -> void* {
    void* p = ws + off;
    off = (off + bytes + 255) & ~(size_t)255;
    return p;
  };
  unsigned short* Wbf  = (unsigned short*)alloc((size_t)DH * KPAD * 2);
  unsigned short* XW   = (unsigned short*)alloc((size_t)M2 * DH * 2);  // [0,MPAD)=feat, rest=aug
  float* S       = (float*)alloc((size_t)N_NODES * KC * 4);
  int*   ecol    = (int*)alloc((size_t)NE * 4);
  float* eval    = (float*)alloc((size_t)NE * 4);
  int*   row_ptr = (int*)alloc((size_t)(N_NODES + 1) * 4);
  int*   cursor  = (int*)alloc((size_t)N_NODES * 4);
  int*   counts  = (int*)alloc((size_t)N_NODES * 4);
  float* exptot  = (float*)alloc((size_t)DH * 4);   // contiguous zero region:
  float* augtot  = (float*)alloc((size_t)DH * 4);   //   exptot | augtot | scal
  float* scal    = (float*)alloc(64 * 4);
  if (off > ws_size) return;  // workspace too small: fail loudly, no OOB

  hipMemsetAsync(counts, 0, (size_t)N_NODES * 4, stream);
  hipMemsetAsync(exptot, 0, (size_t)DH * 4 * 2 + 64 * 4, stream);

  // W1 -> bf16 (tiny)
  k_cvt_pad<<<128, 256, 0, stream>>>(W1, Wbf, DH, N_FEAT, DH, KPAD);

  // CSR build
  k_count<<<(NE + 255) / 256, 256, 0, stream>>>(grow, counts);
  k_scan<<<1, 1024, 0, stream>>>(counts, row_ptr, cursor);
  k_scatter<<<(NE + 255) / 256, 256, 0, stream>>>(grow, gcol, gnv, cursor, ecol, eval);

  // fused-conversion GEMM over both matrices (tile 128x256)
  k_gemm_fused<<<M2 / 128, 512, 0, stream>>>(features, augf, Wbf, XW);

  // persistent combined SpMM + full fused epilogue
  k_spmm_fused<<<SPMM_BLOCKS, 256, 0, stream>>>(row_ptr, ecol, eval,
                                                XW, XW + (size_t)MPAD * DH,
                                                b1, Wt, bt, S, exptot, augtot,
                                                scal + 18, scal + 0);

  // graph stats on assignments
  k_edge<<<512, 256, 0, stream>>>(grow, gcol, gvals, S, scal + 2, scal + 1);

  // final scalar
  k_final<<<1, 256, 0, stream>>>(exptot, augtot, scal, (float*)d_out);
}

// Round 6
// 712.331 us; speedup vs baseline: 1.0797x; 1.0797x over previous
//
#include <hip/hip_runtime.h>
#include <math.h>

// Problem constants (fixed by reference)
#define N_NODES 50000
#define N_FEAT  500
#define DH      256
#define KC      16
#define NE      800000
#define KPAD    512     // N_FEAT padded to MFMA K multiple
#define MPAD    50048   // 391 * 128 (GEMM M tiles)
#define M2      (2 * MPAD)
#define SPMM_BLOCKS 2048

typedef __attribute__((ext_vector_type(8))) short short8;
typedef __attribute__((ext_vector_type(4))) float f32x4;

__device__ __forceinline__ unsigned short f2bf(float f) {
  unsigned u = __float_as_uint(f);
  u += 0x7FFFu + ((u >> 16) & 1u);   // RNE
  return (unsigned short)(u >> 16);
}

__device__ __forceinline__ float bf2f(unsigned short u) {
  return __uint_as_float((unsigned)u << 16);
}

__device__ __forceinline__ float selu_f(float x) {
  return 1.0507009873554805f * (x > 0.f ? x : 1.6732632423543772f * expm1f(x));
}

__device__ __forceinline__ void gload16(const void* g, void* l) {
  __builtin_amdgcn_global_load_lds(
      (const __attribute__((address_space(1))) unsigned int*)g,
      (__attribute__((address_space(3))) unsigned int*)l, 16, 0, 0);
}

// ---- f32 -> bf16 with zero padding (used only for W1) ----
__global__ void k_cvt_pad(const float* __restrict__ in, unsigned short* __restrict__ out,
                          int rin, int cin, int rout, int cout) {
  const int cquads = cout >> 2;
  const long total = (long)rout * cquads;
  for (long idx = (long)blockIdx.x * blockDim.x + threadIdx.x; idx < total;
       idx += (long)gridDim.x * blockDim.x) {
    const int row = (int)(idx / cquads);
    const int c4  = (int)(idx - (long)row * cquads) * 4;
    float x = 0.f, y = 0.f, z = 0.f, w = 0.f;
    if (row < rin && c4 < cin) {
      const float4 v = *(const float4*)(in + (size_t)row * cin + c4);
      x = v.x; y = v.y; z = v.z; w = v.w;
    }
    ushort4 o; o.x = f2bf(x); o.y = f2bf(y); o.z = f2bf(z); o.w = f2bf(w);
    *(ushort4*)(out + (size_t)row * cout + c4) = o;
  }
}

// ---- Fused f32->bf16 GEMM: C[m][n] = sum_k A[m][k]*W[n][k]
//      A = features (rows [0,MPAD)) or aug (rows [MPAD,2*MPAD)), f32 [N][500]
//      W = Wbf bf16 [256][512]; tile 128x256, 512 threads, 8 waves of 64x64. ----
__global__ __launch_bounds__(512, 2) void k_gemm_fused(
    const float* __restrict__ Af, const float* __restrict__ Aa,
    const unsigned short* __restrict__ Wbf, unsigned short* __restrict__ C) {
  __shared__ short As[128 * 64];
  __shared__ short Bs[256 * 64];
  const int t = threadIdx.x;
  const int lane = t & 63, wave = t >> 6;
  const int wr = (wave >> 2) * 64, wc = (wave & 3) * 64;
  const int bm = blockIdx.x * 128;
  const bool isaug = bm >= MPAD;
  const float* __restrict__ src = isaug ? Aa : Af;
  const int row0 = isaug ? bm - MPAD : bm;
  const int lr = lane & 15, lk = (lane >> 4) * 8;
  const int ar = t >> 3, ac = (t & 7) * 8;
  f32x4 acc[4][4] = {};
  for (int kb = 0; kb < KPAD; kb += 64) {
#pragma unroll
    for (int i = 0; i < 4; ++i) {
      const int chunk = i * 512 + t;
      const int rb = chunk >> 3, sub = (chunk & 7) * 8;
      gload16(Wbf + (size_t)rb * KPAD + kb + sub, (void*)(Bs + (size_t)chunk * 8));
    }
#pragma unroll
    for (int h = 0; h < 128; h += 64) {
      const int gr = row0 + ar + h;
      const int c = kb + ac;
      const bool vr = gr < N_NODES;
      float4 u0 = {0.f, 0.f, 0.f, 0.f}, u1 = {0.f, 0.f, 0.f, 0.f};
      const float* arow = src + (size_t)gr * N_FEAT;
      if (vr && c < N_FEAT)     u0 = *(const float4*)(arow + c);
      if (vr && c + 4 < N_FEAT) u1 = *(const float4*)(arow + c + 4);
      short8 w;
      w[0] = (short)f2bf(u0.x); w[1] = (short)f2bf(u0.y);
      w[2] = (short)f2bf(u0.z); w[3] = (short)f2bf(u0.w);
      w[4] = (short)f2bf(u1.x); w[5] = (short)f2bf(u1.y);
      w[6] = (short)f2bf(u1.z); w[7] = (short)f2bf(u1.w);
      *(short8*)(As + (size_t)(ar + h) * 64 + ac) = w;
    }
    __syncthreads();
#pragma unroll
    for (int kk = 0; kk < 64; kk += 32) {
      short8 af[4], bfr[4];
#pragma unroll
      for (int m = 0; m < 4; ++m)
        af[m] = *(const short8*)(As + (wr + m * 16 + lr) * 64 + kk + lk);
#pragma unroll
      for (int n = 0; n < 4; ++n)
        bfr[n] = *(const short8*)(Bs + (wc + n * 16 + lr) * 64 + kk + lk);
#pragma unroll
      for (int m = 0; m < 4; ++m)
#pragma unroll
        for (int n = 0; n < 4; ++n)
          acc[m][n] = __builtin_amdgcn_mfma_f32_16x16x32_bf16(af[m], bfr[n], acc[m][n], 0, 0, 0);
    }
    __syncthreads();
  }
  const int crow = (lane >> 4) * 4, ccol = lane & 15;
#pragma unroll
  for (int m = 0; m < 4; ++m)
#pragma unroll
    for (int n = 0; n < 4; ++n)
#pragma unroll
      for (int r = 0; r < 4; ++r)
        C[(size_t)(bm + wr + m * 16 + crow + r) * DH + (wc + n * 16 + ccol)] =
            f2bf(acc[m][n][r]);
}

// ---- CSR build ----
__global__ void k_count(const int* __restrict__ row, int* __restrict__ counts) {
  const int e = blockIdx.x * blockDim.x + threadIdx.x;
  if (e < NE) atomicAdd(&counts[row[e]], 1);
}

__global__ __launch_bounds__(1024) void k_scan(const int* __restrict__ counts,
                                               int* __restrict__ row_ptr, int* __restrict__ cursor) {
  __shared__ int part[1024];
  const int t = threadIdx.x;
  const int per = (N_NODES + 1023) / 1024;
  const int base = t * per;
  int s = 0;
  for (int i = 0; i < per; ++i) { const int j = base + i; if (j < N_NODES) s += counts[j]; }
  part[t] = s;
  __syncthreads();
  for (int off = 1; off < 1024; off <<= 1) {
    const int v = (t >= off) ? part[t - off] : 0;
    __syncthreads();
    part[t] += v;
    __syncthreads();
  }
  int run = (t == 0) ? 0 : part[t - 1];
  for (int i = 0; i < per; ++i) {
    const int j = base + i;
    if (j < N_NODES) { row_ptr[j] = run; cursor[j] = run; run += counts[j]; }
  }
  if (t == 1023) row_ptr[N_NODES] = part[1023];
}

__global__ void k_scatter(const int* __restrict__ row, const int* __restrict__ col,
                          const float* __restrict__ gnv, int* __restrict__ cursor,
                          int* __restrict__ ecol, float* __restrict__ eval) {
  const int e = blockIdx.x * blockDim.x + threadIdx.x;
  if (e < NE) {
    const int p = atomicAdd(&cursor[row[e]], 1);
    ecol[p] = col[e];
    eval[p] = gnv[e];
  }
}

// ---- Persistent combined SpMM (features + aug) + full fused epilogue.
//      2048 blocks, one wave per row, grid-stride over rows (~6 rows/wave).
//      Half-wave covers a 512B bf16 row (lane: 8 cols). Straightline gathers
//      (8 edges/iter, compiler-scheduled). exp/aug/dot/cs accumulate in
//      REGISTERS across rows; one LDS+global flush per block.
//      launch_bounds(256,3): ~170-VGPR cap — R5's (256,4) caused scratch
//      spills (WRITE_SIZE 408MB) that tripled FETCH and 1.7x'd time. ----
__global__ __launch_bounds__(256, 3) void k_spmm_fused(
    const int* __restrict__ row_ptr, const int* __restrict__ ecol, const float* __restrict__ eval,
    const unsigned short* __restrict__ XWf, const unsigned short* __restrict__ XWa,
    const float* __restrict__ b1, const float* __restrict__ Wt, const float* __restrict__ bt,
    float* __restrict__ S, float* __restrict__ exptot, float* __restrict__ augtot,
    float* __restrict__ csg, float* __restrict__ dotAG) {
  __shared__ float Wl[KC * DH];
  __shared__ float btl[KC];
  __shared__ float expacc[DH];
  __shared__ float augacc[DH];
  __shared__ float csacc[KC];
  __shared__ float dacc;
  for (int i4 = threadIdx.x; i4 < KC * DH / 4; i4 += 256)
    ((float4*)Wl)[i4] = ((const float4*)Wt)[i4];
  if (threadIdx.x < KC) { btl[threadIdx.x] = bt[threadIdx.x]; csacc[threadIdx.x] = 0.f; }
  expacc[threadIdx.x] = 0.f;
  augacc[threadIdx.x] = 0.f;
  if (threadIdx.x == 0) dacc = 0.f;
  __syncthreads();

  const int wave = threadIdx.x >> 6, lane = threadIdx.x & 63;
  const int half = lane >> 5;
  const int c0   = (lane & 31) * 8;
  const unsigned short* XF = XWf + c0;
  const unsigned short* XA = XWa + c0;
  const float4 blo = *(const float4*)(b1 + c0);
  const float4 bhi = *(const float4*)(b1 + c0 + 4);

  float lexp[8] = {0.f, 0.f, 0.f, 0.f, 0.f, 0.f, 0.f, 0.f};
  float laug[8] = {0.f, 0.f, 0.f, 0.f, 0.f, 0.f, 0.f, 0.f};
  float ldot = 0.f, lcs = 0.f;

  for (int i = blockIdx.x * 4 + wave; i < N_NODES; i += SPMM_BLOCKS * 4) {
    const int s = row_ptr[i], e = row_ptr[i + 1];
    float accf[8] = {0.f, 0.f, 0.f, 0.f, 0.f, 0.f, 0.f, 0.f};
    float acca[8] = {0.f, 0.f, 0.f, 0.f, 0.f, 0.f, 0.f, 0.f};
    for (int pb = s; pb < e; pb += 8) {
      int ci[4]; float vi[4];
#pragma unroll
      for (int j = 0; j < 4; ++j) {
        const int q = pb + 2 * j + half;
        const bool act = q < e;
        const int qi = act ? q : s;
        ci[j] = ecol[qi];
        vi[j] = act ? eval[qi] : 0.f;
      }
      short8 xf[4], xa[4];
#pragma unroll
      for (int j = 0; j < 4; ++j) {
        xf[j] = *(const short8*)(XF + (size_t)ci[j] * DH);
        xa[j] = *(const short8*)(XA + (size_t)ci[j] * DH);
      }
#pragma unroll
      for (int j = 0; j < 4; ++j)
#pragma unroll
        for (int u = 0; u < 8; ++u) {
          accf[u] += vi[j] * bf2f((unsigned short)xf[j][u]);
          acca[u] += vi[j] * bf2f((unsigned short)xa[j][u]);
        }
    }
    // fold the two halves (both get full row sums)
#pragma unroll
    for (int u = 0; u < 8; ++u) {
      accf[u] += __shfl_xor(accf[u], 32);
      acca[u] += __shfl_xor(acca[u], 32);
    }

    // bias + selu
    float of[8], oa[8];
    of[0] = selu_f(accf[0] + blo.x); of[1] = selu_f(accf[1] + blo.y);
    of[2] = selu_f(accf[2] + blo.z); of[3] = selu_f(accf[3] + blo.w);
    of[4] = selu_f(accf[4] + bhi.x); of[5] = selu_f(accf[5] + bhi.y);
    of[6] = selu_f(accf[6] + bhi.z); of[7] = selu_f(accf[7] + bhi.w);
    oa[0] = selu_f(acca[0] + blo.x); oa[1] = selu_f(acca[1] + blo.y);
    oa[2] = selu_f(acca[2] + blo.z); oa[3] = selu_f(acca[3] + blo.w);
    oa[4] = selu_f(acca[4] + bhi.x); oa[5] = selu_f(acca[5] + bhi.y);
    oa[6] = selu_f(acca[6] + bhi.z); oa[7] = selu_f(acca[7] + bhi.w);

    // register accumulation across rows (halves duplicate; flushed from half 0)
#pragma unroll
    for (int u = 0; u < 8; ++u) {
      lexp[u] += expf(of[u]);
      laug[u] += oa[u];
      ldot += oa[u] * of[u];
    }

    // assignments = softmax(of @ Wt^T + bt)
    float lg[KC];
#pragma unroll
    for (int k = 0; k < KC; ++k) {
      const float4 wlo = *(const float4*)(Wl + k * DH + c0);
      const float4 whi = *(const float4*)(Wl + k * DH + c0 + 4);
      lg[k] = of[0] * wlo.x + of[1] * wlo.y + of[2] * wlo.z + of[3] * wlo.w
            + of[4] * whi.x + of[5] * whi.y + of[6] * whi.z + of[7] * whi.w;
    }
#pragma unroll
    for (int off = 16; off; off >>= 1)
#pragma unroll
      for (int k = 0; k < KC; ++k) lg[k] += __shfl_xor(lg[k], off);
    float mx = -3.4e38f;
#pragma unroll
    for (int k = 0; k < KC; ++k) { lg[k] += btl[k]; mx = fmaxf(mx, lg[k]); }
    float se = 0.f;
#pragma unroll
    for (int k = 0; k < KC; ++k) { lg[k] = expf(lg[k] - mx); se += lg[k]; }
    const float inv = 1.f / se;
    float myv = 0.f;
#pragma unroll
    for (int k = 0; k < KC; ++k) if (lane == k) myv = lg[k];
    if (lane < KC) {
      const float sv = myv * inv;
      S[(size_t)i * KC + lane] = sv;
      lcs += sv;
    }
  }

  // ---- block-level flush ----
#pragma unroll
  for (int off = 16; off; off >>= 1) ldot += __shfl_xor(ldot, off);
  if (lane == 0) atomicAdd(&dacc, ldot);
  if (half == 0) {
#pragma unroll
    for (int u = 0; u < 8; ++u) {
      atomicAdd(&expacc[c0 + u], lexp[u]);
      atomicAdd(&augacc[c0 + u], laug[u]);
    }
  }
  if (lane < KC) atomicAdd(&csacc[lane], lcs);
  __syncthreads();
  atomicAdd(&exptot[threadIdx.x], expacc[threadIdx.x]);
  atomicAdd(&augtot[threadIdx.x], augacc[threadIdx.x]);
  if (threadIdx.x < KC) atomicAdd(&csg[threadIdx.x], csacc[threadIdx.x]);
  if (threadIdx.x == 0) atomicAdd(dotAG, dacc);
}

// ---- edge stats: tp = sum_e v*dot16(S[row],S[col]); nl[k] = sum_e v*S[col,k] ----
__global__ __launch_bounds__(256) void k_edge(const int* __restrict__ grow, const int* __restrict__ gcol,
                                              const float* __restrict__ gvals, const float* __restrict__ S,
                                              float* __restrict__ nl, float* __restrict__ tp) {
  float ltp = 0.f;
  float lnl[KC];
#pragma unroll
  for (int k = 0; k < KC; ++k) lnl[k] = 0.f;
  for (long e = (long)blockIdx.x * 256 + threadIdx.x; e < NE; e += (long)gridDim.x * 256) {
    const int r = grow[e], c = gcol[e];
    const float v = gvals[e];
    const float4* sr = (const float4*)(S + (size_t)r * KC);
    const float4* sc = (const float4*)(S + (size_t)c * KC);
    const float4 a0 = sr[0], a1 = sr[1], a2 = sr[2], a3 = sr[3];
    const float4 b0 = sc[0], b1v = sc[1], b2 = sc[2], b3 = sc[3];
    const float dot = a0.x * b0.x + a0.y * b0.y + a0.z * b0.z + a0.w * b0.w
                    + a1.x * b1v.x + a1.y * b1v.y + a1.z * b1v.z + a1.w * b1v.w
                    + a2.x * b2.x + a2.y * b2.y + a2.z * b2.z + a2.w * b2.w
                    + a3.x * b3.x + a3.y * b3.y + a3.z * b3.z + a3.w * b3.w;
    ltp += v * dot;
    lnl[0] += v * b0.x;  lnl[1] += v * b0.y;  lnl[2] += v * b0.z;  lnl[3] += v * b0.w;
    lnl[4] += v * b1v.x; lnl[5] += v * b1v.y; lnl[6] += v * b1v.z; lnl[7] += v * b1v.w;
    lnl[8] += v * b2.x;  lnl[9] += v * b2.y;  lnl[10] += v * b2.z; lnl[11] += v * b2.w;
    lnl[12] += v * b3.x; lnl[13] += v * b3.y; lnl[14] += v * b3.z; lnl[15] += v * b3.w;
  }
#pragma unroll
  for (int off = 32; off; off >>= 1) {
    ltp += __shfl_xor(ltp, off);
#pragma unroll
    for (int k = 0; k < KC; ++k) lnl[k] += __shfl_xor(lnl[k], off);
  }
  __shared__ float wred[4][KC + 1];
  const int wave = threadIdx.x >> 6, lane = threadIdx.x & 63;
  if (lane == 0) {
    wred[wave][0] = ltp;
#pragma unroll
    for (int k = 0; k < KC; ++k) wred[wave][1 + k] = lnl[k];
  }
  __syncthreads();
  if (threadIdx.x < KC + 1) {
    const float s = wred[0][threadIdx.x] + wred[1][threadIdx.x] + wred[2][threadIdx.x] + wred[3][threadIdx.x];
    if (threadIdx.x == 0) atomicAdd(tp, s);
    else atomicAdd(&nl[threadIdx.x - 1], s);
  }
}

// ---- final scalar assembly ----
// scal layout: [0]=dotAG, [1]=tp, [2..17]=nl, [18..33]=cs
__global__ void k_final(const float* __restrict__ exptot, const float* __restrict__ augtot,
                        const float* __restrict__ scal, float* __restrict__ out) {
  const int d = threadIdx.x;
  const float L = logf(exptot[d]);
  const float sa = augtot[d];
  __shared__ float red[DH];
  red[d] = L * sa;
  __syncthreads();
  for (int off = 128; off; off >>= 1) {
    if (d < off) red[d] += red[d + off];
    __syncthreads();
  }
  if (d == 0) {
    const float sumLA = red[0];
    const float dotAG = scal[0];
    const float tp = scal[1];
    float nl2 = 0.f, cs2 = 0.f;
#pragma unroll
    for (int k = 0; k < KC; ++k) {
      nl2 += scal[2 + k] * scal[2 + k];
      cs2 += scal[18 + k] * scal[18 + k];
    }
    const float fE = (float)NE;
    const float con = -(dotAG - sumLA) / (float)DH;
    const float trn = nl2 / (2.f * fE);
    const float spectral = -(tp - trn) / (2.f * fE);
    const float cluster = (sqrtf(cs2) / (float)N_NODES * 4.f - 1.f);
    out[0] = spectral + cluster + 0.5f * con;
  }
}

extern "C" void kernel_launch(void* const* d_in, const int* in_sizes, int n_in,
                              void* d_out, int out_size, void* d_ws, size_t ws_size,
                              hipStream_t stream) {
  const float* features = (const float*)d_in[0];
  const float* augf     = (const float*)d_in[1];
  const int*   grow     = (const int*)d_in[2];
  const int*   gcol     = (const int*)d_in[3];
  const float* gvals    = (const float*)d_in[4];
  const float* gnv      = (const float*)d_in[5];
  const float* W1       = (const float*)d_in[8];
  const float* b1       = (const float*)d_in[9];
  const float* Wt       = (const float*)d_in[10];
  const float* bt       = (const float*)d_in[11];

  char* ws = (char*)d_ws;
  size_t off = 0;
  auto alloc = [&](size_t bytes) -> void* {
    void* p = ws + off;
    off = (off + bytes + 255) & ~(size_t)255;
    return p;
  };
  unsigned short* Wbf  = (unsigned short*)alloc((size_t)DH * KPAD * 2);
  unsigned short* XW   = (unsigned short*)alloc((size_t)M2 * DH * 2);  // [0,MPAD)=feat, rest=aug
  float* S       = (float*)alloc((size_t)N_NODES * KC * 4);
  int*   ecol    = (int*)alloc((size_t)NE * 4);
  float* eval    = (float*)alloc((size_t)NE * 4);
  int*   row_ptr = (int*)alloc((size_t)(N_NODES + 1) * 4);
  int*   cursor  = (int*)alloc((size_t)N_NODES * 4);
  int*   counts  = (int*)alloc((size_t)N_NODES * 4);
  float* exptot  = (float*)alloc((size_t)DH * 4);   // contiguous zero region:
  float* augtot  = (float*)alloc((size_t)DH * 4);   //   exptot | augtot | scal
  float* scal    = (float*)alloc(64 * 4);
  if (off > ws_size) return;  // workspace too small: fail loudly, no OOB

  hipMemsetAsync(counts, 0, (size_t)N_NODES * 4, stream);
  hipMemsetAsync(exptot, 0, (size_t)DH * 4 * 2 + 64 * 4, stream);

  // W1 -> bf16 (tiny)
  k_cvt_pad<<<128, 256, 0, stream>>>(W1, Wbf, DH, N_FEAT, DH, KPAD);

  // CSR build
  k_count<<<(NE + 255) / 256, 256, 0, stream>>>(grow, counts);
  k_scan<<<1, 1024, 0, stream>>>(counts, row_ptr, cursor);
  k_scatter<<<(NE + 255) / 256, 256, 0, stream>>>(grow, gcol, gnv, cursor, ecol, eval);

  // fused-conversion GEMM over both matrices (tile 128x256)
  k_gemm_fused<<<M2 / 128, 512, 0, stream>>>(features, augf, Wbf, XW);

  // persistent combined SpMM + full fused epilogue
  k_spmm_fused<<<SPMM_BLOCKS, 256, 0, stream>>>(row_ptr, ecol, eval,
                                                XW, XW + (size_t)MPAD * DH,
                                                b1, Wt, bt, S, exptot, augtot,
                                                scal + 18, scal + 0);

  // graph stats on assignments
  k_edge<<<512, 256, 0, stream>>>(grow, gcol, gvals, S, scal + 2, scal + 1);

  // final scalar
  k_final<<<1, 256, 0, stream>>>(exptot, augtot, scal, (float*)d_out);
}

// Round 7
// 617.306 us; speedup vs baseline: 1.2459x; 1.1539x over previous
//
#include <hip/hip_runtime.h>
#include <math.h>

// Problem constants (fixed by reference)
#define N_NODES 50000
#define N_FEAT  500
#define DH      256
#define KC      16
#define NE      800000
#define KPAD    512     // N_FEAT padded to MFMA K multiple
#define MPAD    50048   // 391 * 128 (GEMM M tiles)
#define M2      (2 * MPAD)
#define SLICE_COLS 32   // D-slice per XCD: 50048*32*2B = 3.2MB fits 4MB L2
#define NSLICE  8       // 256 / 32
#define SPMM_BLOCKS 2048
#define ROWS_PER_BLK 196  // ceil(50000/256)

typedef __attribute__((ext_vector_type(8))) short short8;
typedef __attribute__((ext_vector_type(4))) float f32x4;

__device__ __forceinline__ unsigned short f2bf(float f) {
  unsigned u = __float_as_uint(f);
  u += 0x7FFFu + ((u >> 16) & 1u);   // RNE
  return (unsigned short)(u >> 16);
}

__device__ __forceinline__ float bf2f(unsigned short u) {
  return __uint_as_float((unsigned)u << 16);
}

__device__ __forceinline__ float selu_f(float x) {
  return 1.0507009873554805f * (x > 0.f ? x : 1.6732632423543772f * expm1f(x));
}

__device__ __forceinline__ void gload16(const void* g, void* l) {
  __builtin_amdgcn_global_load_lds(
      (const __attribute__((address_space(1))) unsigned int*)g,
      (__attribute__((address_space(3))) unsigned int*)l, 16, 0, 0);
}

// ---- f32 -> bf16 with zero padding (used only for W1) ----
__global__ void k_cvt_pad(const float* __restrict__ in, unsigned short* __restrict__ out,
                          int rin, int cin, int rout, int cout) {
  const int cquads = cout >> 2;
  const long total = (long)rout * cquads;
  for (long idx = (long)blockIdx.x * blockDim.x + threadIdx.x; idx < total;
       idx += (long)gridDim.x * blockDim.x) {
    const int row = (int)(idx / cquads);
    const int c4  = (int)(idx - (long)row * cquads) * 4;
    float x = 0.f, y = 0.f, z = 0.f, w = 0.f;
    if (row < rin && c4 < cin) {
      const float4 v = *(const float4*)(in + (size_t)row * cin + c4);
      x = v.x; y = v.y; z = v.z; w = v.w;
    }
    ushort4 o; o.x = f2bf(x); o.y = f2bf(y); o.z = f2bf(z); o.w = f2bf(w);
    *(ushort4*)(out + (size_t)row * cout + c4) = o;
  }
}

// ---- Fused f32->bf16 GEMM: out[m][n] = sum_k A[m][k]*W[n][k]
//      A = features (rows [0,MPAD)) or aug ([MPAD,2*MPAD)), f32 [N][500]
//      Output layout: XWs[pair][node][32], pair = isaug*8 + (col>>5).
//      (slice-major so each XCD's gather working set is contiguous 3.2MB) ----
__global__ __launch_bounds__(512, 2) void k_gemm_fused(
    const float* __restrict__ Af, const float* __restrict__ Aa,
    const unsigned short* __restrict__ Wbf, unsigned short* __restrict__ XWs) {
  __shared__ short As[128 * 64];
  __shared__ short Bs[256 * 64];
  const int t = threadIdx.x;
  const int lane = t & 63, wave = t >> 6;
  const int wr = (wave >> 2) * 64, wc = (wave & 3) * 64;
  const int bm = blockIdx.x * 128;
  const bool isaug = bm >= MPAD;
  const float* __restrict__ src = isaug ? Aa : Af;
  const int row0 = isaug ? bm - MPAD : bm;
  const int lr = lane & 15, lk = (lane >> 4) * 8;
  const int ar = t >> 3, ac = (t & 7) * 8;
  f32x4 acc[4][4] = {};
  for (int kb = 0; kb < KPAD; kb += 64) {
#pragma unroll
    for (int i = 0; i < 4; ++i) {
      const int chunk = i * 512 + t;
      const int rb = chunk >> 3, sub = (chunk & 7) * 8;
      gload16(Wbf + (size_t)rb * KPAD + kb + sub, (void*)(Bs + (size_t)chunk * 8));
    }
#pragma unroll
    for (int h = 0; h < 128; h += 64) {
      const int gr = row0 + ar + h;
      const int c = kb + ac;
      const bool vr = gr < N_NODES;
      float4 u0 = {0.f, 0.f, 0.f, 0.f}, u1 = {0.f, 0.f, 0.f, 0.f};
      const float* arow = src + (size_t)gr * N_FEAT;
      if (vr && c < N_FEAT)     u0 = *(const float4*)(arow + c);
      if (vr && c + 4 < N_FEAT) u1 = *(const float4*)(arow + c + 4);
      short8 w;
      w[0] = (short)f2bf(u0.x); w[1] = (short)f2bf(u0.y);
      w[2] = (short)f2bf(u0.z); w[3] = (short)f2bf(u0.w);
      w[4] = (short)f2bf(u1.x); w[5] = (short)f2bf(u1.y);
      w[6] = (short)f2bf(u1.z); w[7] = (short)f2bf(u1.w);
      *(short8*)(As + (size_t)(ar + h) * 64 + ac) = w;
    }
    __syncthreads();
#pragma unroll
    for (int kk = 0; kk < 64; kk += 32) {
      short8 af[4], bfr[4];
#pragma unroll
      for (int mi = 0; mi < 4; ++mi)
        af[mi] = *(const short8*)(As + (wr + mi * 16 + lr) * 64 + kk + lk);
#pragma unroll
      for (int n = 0; n < 4; ++n)
        bfr[n] = *(const short8*)(Bs + (wc + n * 16 + lr) * 64 + kk + lk);
#pragma unroll
      for (int mi = 0; mi < 4; ++mi)
#pragma unroll
        for (int n = 0; n < 4; ++n)
          acc[mi][n] = __builtin_amdgcn_mfma_f32_16x16x32_bf16(af[mi], bfr[n], acc[mi][n], 0, 0, 0);
    }
    __syncthreads();
  }
  const int crow = (lane >> 4) * 4, ccol = lane & 15;
  const int pbase = isaug ? NSLICE : 0;
#pragma unroll
  for (int mi = 0; mi < 4; ++mi)
#pragma unroll
    for (int n = 0; n < 4; ++n) {
      const int col = wc + n * 16 + ccol;
      const int pp = pbase + (col >> 5);
      const int cc = col & 31;
#pragma unroll
      for (int r = 0; r < 4; ++r) {
        const int node = row0 + wr + mi * 16 + crow + r;
        XWs[((size_t)pp * MPAD + node) * SLICE_COLS + cc] = f2bf(acc[mi][n][r]);
      }
    }
}

// ---- CSR build ----
__global__ void k_count(const int* __restrict__ row, int* __restrict__ counts) {
  const int e = blockIdx.x * blockDim.x + threadIdx.x;
  if (e < NE) atomicAdd(&counts[row[e]], 1);
}

__global__ __launch_bounds__(1024) void k_scan(const int* __restrict__ counts,
                                               int* __restrict__ row_ptr, int* __restrict__ cursor) {
  __shared__ int part[1024];
  const int t = threadIdx.x;
  const int per = (N_NODES + 1023) / 1024;
  const int base = t * per;
  int s = 0;
  for (int i = 0; i < per; ++i) { const int j = base + i; if (j < N_NODES) s += counts[j]; }
  part[t] = s;
  __syncthreads();
  for (int off = 1; off < 1024; off <<= 1) {
    const int v = (t >= off) ? part[t - off] : 0;
    __syncthreads();
    part[t] += v;
    __syncthreads();
  }
  int run = (t == 0) ? 0 : part[t - 1];
  for (int i = 0; i < per; ++i) {
    const int j = base + i;
    if (j < N_NODES) { row_ptr[j] = run; cursor[j] = run; run += counts[j]; }
  }
  if (t == 1023) row_ptr[N_NODES] = part[1023];
}

__global__ void k_scatter(const int* __restrict__ row, const int* __restrict__ col,
                          const float* __restrict__ gnv, int* __restrict__ cursor,
                          int* __restrict__ ecol, float* __restrict__ eval) {
  const int e = blockIdx.x * blockDim.x + threadIdx.x;
  if (e < NE) {
    const int p = atomicAdd(&cursor[row[e]], 1);
    ecol[p] = col[e];
    eval[p] = gnv[e];
  }
}

// ---- XCD-sliced SpMM + bias + selu -> O (bf16).
//      Block b: slice s = b&7 (pinned to XCD s by the round-robin dispatch),
//      rows [ (b>>3)*196, +196 ). Phase 0: feat, phase 1: aug.
//      Working set per phase = XWs slice = 3.2MB -> resident in that XCD's L2.
//      Wave: 16 row-groups of 4 lanes; lane covers 8 cols (16B gathers).
//      No cross-lane reduce, no atomics, ~40 VGPR. ----
__global__ __launch_bounds__(256, 4) void k_spmm_slice(
    const int* __restrict__ row_ptr, const int* __restrict__ ecol, const float* __restrict__ eval,
    const unsigned short* __restrict__ XWs, const float* __restrict__ b1,
    unsigned short* __restrict__ O) {
  const int slice = blockIdx.x & 7;
  const int rblk  = blockIdx.x >> 3;
  const int r0 = rblk * ROWS_PER_BLK;
  const int r1 = min(r0 + ROWS_PER_BLK, N_NODES);
  const int wave = threadIdx.x >> 6, lane = threadIdx.x & 63;
  const int g = lane >> 2, sub = lane & 3;
  const int scol = slice * SLICE_COLS + sub * 8;

  const float4 b0 = *(const float4*)(b1 + scol);
  const float4 b4 = *(const float4*)(b1 + scol + 4);

  for (int ph = 0; ph < 2; ++ph) {
    const unsigned short* __restrict__ Xb =
        XWs + ((size_t)(ph * NSLICE + slice) * MPAD) * SLICE_COLS + sub * 8;
    unsigned short* __restrict__ Ob = O + (size_t)ph * N_NODES * DH;
    for (int rb = r0; rb < r1; rb += 64) {
      const int row = rb + wave * 16 + g;
      if (row >= r1) continue;
      const int s = row_ptr[row], e = row_ptr[row + 1];
      float acc[8] = {0.f, 0.f, 0.f, 0.f, 0.f, 0.f, 0.f, 0.f};
      int p = s;
      for (; p + 1 < e; p += 2) {
        const int   c0 = ecol[p],  c1 = ecol[p + 1];
        const float v0 = eval[p],  v1 = eval[p + 1];
        const short8 x0 = *(const short8*)(Xb + (size_t)c0 * SLICE_COLS);
        const short8 x1 = *(const short8*)(Xb + (size_t)c1 * SLICE_COLS);
#pragma unroll
        for (int u = 0; u < 8; ++u) {
          acc[u] += v0 * bf2f((unsigned short)x0[u]);
          acc[u] += v1 * bf2f((unsigned short)x1[u]);
        }
      }
      if (p < e) {
        const int   c0 = ecol[p];
        const float v0 = eval[p];
        const short8 x0 = *(const short8*)(Xb + (size_t)c0 * SLICE_COLS);
#pragma unroll
        for (int u = 0; u < 8; ++u) acc[u] += v0 * bf2f((unsigned short)x0[u]);
      }
      short8 o;
      o[0] = (short)f2bf(selu_f(acc[0] + b0.x));
      o[1] = (short)f2bf(selu_f(acc[1] + b0.y));
      o[2] = (short)f2bf(selu_f(acc[2] + b0.z));
      o[3] = (short)f2bf(selu_f(acc[3] + b0.w));
      o[4] = (short)f2bf(selu_f(acc[4] + b4.x));
      o[5] = (short)f2bf(selu_f(acc[5] + b4.y));
      o[6] = (short)f2bf(selu_f(acc[6] + b4.z));
      o[7] = (short)f2bf(selu_f(acc[7] + b4.w));
      *(short8*)(Ob + (size_t)row * DH + scol) = o;
    }
  }
}

// ---- Epilogue over O: S softmax, exp-colsums, aug-colsums, dot, cluster sizes.
//      One wave per row (lane: 4 cols); Wt read from global (L1-resident 16KB). ----
__global__ __launch_bounds__(256, 4) void k_post(
    const unsigned short* __restrict__ O, const float* __restrict__ Wt,
    const float* __restrict__ bt, float* __restrict__ S,
    float* __restrict__ exptot, float* __restrict__ augtot,
    float* __restrict__ csg, float* __restrict__ dotAG) {
  __shared__ float expacc[DH];
  __shared__ float augacc[DH];
  __shared__ float csacc[KC];
  __shared__ float dacc;
  expacc[threadIdx.x] = 0.f;
  augacc[threadIdx.x] = 0.f;
  if (threadIdx.x < KC) csacc[threadIdx.x] = 0.f;
  if (threadIdx.x == 0) dacc = 0.f;
  __syncthreads();

  const int wave = threadIdx.x >> 6, lane = threadIdx.x & 63;
  const int c0 = lane * 4;
  const unsigned short* Of = O;
  const unsigned short* Oa = O + (size_t)N_NODES * DH;

  float lexp[4] = {0.f, 0.f, 0.f, 0.f};
  float laug[4] = {0.f, 0.f, 0.f, 0.f};
  float ldot = 0.f, lcs = 0.f;
  const float btk = (lane < KC) ? bt[lane] : 0.f;

  for (int i = blockIdx.x * 4 + wave; i < N_NODES; i += SPMM_BLOCKS * 4) {
    const ushort4 fu = *(const ushort4*)(Of + (size_t)i * DH + c0);
    const ushort4 au = *(const ushort4*)(Oa + (size_t)i * DH + c0);
    const float of[4] = {bf2f(fu.x), bf2f(fu.y), bf2f(fu.z), bf2f(fu.w)};
    const float oa[4] = {bf2f(au.x), bf2f(au.y), bf2f(au.z), bf2f(au.w)};
#pragma unroll
    for (int u = 0; u < 4; ++u) {
      lexp[u] += expf(of[u]);
      laug[u] += oa[u];
      ldot += of[u] * oa[u];
    }
    // lg[k] = of . Wt[k] (full 256-col dot via 64-lane reduce)
    float lg[KC];
#pragma unroll
    for (int k = 0; k < KC; ++k) {
      const float4 w = *(const float4*)(Wt + (size_t)k * DH + c0);
      lg[k] = of[0] * w.x + of[1] * w.y + of[2] * w.z + of[3] * w.w;
    }
#pragma unroll
    for (int off = 32; off; off >>= 1)
#pragma unroll
      for (int k = 0; k < KC; ++k) lg[k] += __shfl_xor(lg[k], off);
    float mx = -3.4e38f;
#pragma unroll
    for (int k = 0; k < KC; ++k) { lg[k] += (k == 0 ? 0.f : 0.f); }
    // add bias and softmax
    float se = 0.f;
    {
#pragma unroll
      for (int k = 0; k < KC; ++k) lg[k] += __shfl(btk, k);  // bt[k] broadcast
#pragma unroll
      for (int k = 0; k < KC; ++k) mx = fmaxf(mx, lg[k]);
#pragma unroll
      for (int k = 0; k < KC; ++k) { lg[k] = expf(lg[k] - mx); se += lg[k]; }
    }
    const float inv = 1.f / se;
    float myv = 0.f;
#pragma unroll
    for (int k = 0; k < KC; ++k) if (lane == k) myv = lg[k];
    if (lane < KC) {
      const float sv = myv * inv;
      S[(size_t)i * KC + lane] = sv;
      lcs += sv;
    }
  }

  // flush
#pragma unroll
  for (int off = 32; off; off >>= 1) ldot += __shfl_xor(ldot, off);
  if (lane == 0) atomicAdd(&dacc, ldot);
#pragma unroll
  for (int u = 0; u < 4; ++u) {
    atomicAdd(&expacc[c0 + u], lexp[u]);
    atomicAdd(&augacc[c0 + u], laug[u]);
  }
  if (lane < KC) atomicAdd(&csacc[lane], lcs);
  __syncthreads();
  atomicAdd(&exptot[threadIdx.x], expacc[threadIdx.x]);
  atomicAdd(&augtot[threadIdx.x], augacc[threadIdx.x]);
  if (threadIdx.x < KC) atomicAdd(&csg[threadIdx.x], csacc[threadIdx.x]);
  if (threadIdx.x == 0) atomicAdd(dotAG, dacc);
}

// ---- edge stats: tp = sum_e v*dot16(S[row],S[col]); nl[k] = sum_e v*S[col,k] ----
__global__ __launch_bounds__(256) void k_edge(const int* __restrict__ grow, const int* __restrict__ gcol,
                                              const float* __restrict__ gvals, const float* __restrict__ S,
                                              float* __restrict__ nl, float* __restrict__ tp) {
  float ltp = 0.f;
  float lnl[KC];
#pragma unroll
  for (int k = 0; k < KC; ++k) lnl[k] = 0.f;
  for (long e = (long)blockIdx.x * 256 + threadIdx.x; e < NE; e += (long)gridDim.x * 256) {
    const int r = grow[e], c = gcol[e];
    const float v = gvals[e];
    const float4* sr = (const float4*)(S + (size_t)r * KC);
    const float4* sc = (const float4*)(S + (size_t)c * KC);
    const float4 a0 = sr[0], a1 = sr[1], a2 = sr[2], a3 = sr[3];
    const float4 b0 = sc[0], b1v = sc[1], b2 = sc[2], b3 = sc[3];
    const float dot = a0.x * b0.x + a0.y * b0.y + a0.z * b0.z + a0.w * b0.w
                    + a1.x * b1v.x + a1.y * b1v.y + a1.z * b1v.z + a1.w * b1v.w
                    + a2.x * b2.x + a2.y * b2.y + a2.z * b2.z + a2.w * b2.w
                    + a3.x * b3.x + a3.y * b3.y + a3.z * b3.z + a3.w * b3.w;
    ltp += v * dot;
    lnl[0] += v * b0.x;  lnl[1] += v * b0.y;  lnl[2] += v * b0.z;  lnl[3] += v * b0.w;
    lnl[4] += v * b1v.x; lnl[5] += v * b1v.y; lnl[6] += v * b1v.z; lnl[7] += v * b1v.w;
    lnl[8] += v * b2.x;  lnl[9] += v * b2.y;  lnl[10] += v * b2.z; lnl[11] += v * b2.w;
    lnl[12] += v * b3.x; lnl[13] += v * b3.y; lnl[14] += v * b3.z; lnl[15] += v * b3.w;
  }
#pragma unroll
  for (int off = 32; off; off >>= 1) {
    ltp += __shfl_xor(ltp, off);
#pragma unroll
    for (int k = 0; k < KC; ++k) lnl[k] += __shfl_xor(lnl[k], off);
  }
  __shared__ float wred[4][KC + 1];
  const int wave = threadIdx.x >> 6, lane = threadIdx.x & 63;
  if (lane == 0) {
    wred[wave][0] = ltp;
#pragma unroll
    for (int k = 0; k < KC; ++k) wred[wave][1 + k] = lnl[k];
  }
  __syncthreads();
  if (threadIdx.x < KC + 1) {
    const float s = wred[0][threadIdx.x] + wred[1][threadIdx.x] + wred[2][threadIdx.x] + wred[3][threadIdx.x];
    if (threadIdx.x == 0) atomicAdd(tp, s);
    else atomicAdd(&nl[threadIdx.x - 1], s);
  }
}

// ---- final scalar assembly ----
// scal layout: [0]=dotAG, [1]=tp, [2..17]=nl, [18..33]=cs
__global__ void k_final(const float* __restrict__ exptot, const float* __restrict__ augtot,
                        const float* __restrict__ scal, float* __restrict__ out) {
  const int d = threadIdx.x;
  const float L = logf(exptot[d]);
  const float sa = augtot[d];
  __shared__ float red[DH];
  red[d] = L * sa;
  __syncthreads();
  for (int off = 128; off; off >>= 1) {
    if (d < off) red[d] += red[d + off];
    __syncthreads();
  }
  if (d == 0) {
    const float sumLA = red[0];
    const float dotAG = scal[0];
    const float tp = scal[1];
    float nl2 = 0.f, cs2 = 0.f;
#pragma unroll
    for (int k = 0; k < KC; ++k) {
      nl2 += scal[2 + k] * scal[2 + k];
      cs2 += scal[18 + k] * scal[18 + k];
    }
    const float fE = (float)NE;
    const float con = -(dotAG - sumLA) / (float)DH;
    const float trn = nl2 / (2.f * fE);
    const float spectral = -(tp - trn) / (2.f * fE);
    const float cluster = (sqrtf(cs2) / (float)N_NODES * 4.f - 1.f);
    out[0] = spectral + cluster + 0.5f * con;
  }
}

extern "C" void kernel_launch(void* const* d_in, const int* in_sizes, int n_in,
                              void* d_out, int out_size, void* d_ws, size_t ws_size,
                              hipStream_t stream) {
  const float* features = (const float*)d_in[0];
  const float* augf     = (const float*)d_in[1];
  const int*   grow     = (const int*)d_in[2];
  const int*   gcol     = (const int*)d_in[3];
  const float* gvals    = (const float*)d_in[4];
  const float* gnv      = (const float*)d_in[5];
  const float* W1       = (const float*)d_in[8];
  const float* b1       = (const float*)d_in[9];
  const float* Wt       = (const float*)d_in[10];
  const float* bt       = (const float*)d_in[11];

  char* ws = (char*)d_ws;
  size_t off = 0;
  auto alloc = [&](size_t bytes) -> void* {
    void* p = ws + off;
    off = (off + bytes + 255) & ~(size_t)255;
    return p;
  };
  unsigned short* Wbf  = (unsigned short*)alloc((size_t)DH * KPAD * 2);
  unsigned short* XWs  = (unsigned short*)alloc((size_t)16 * MPAD * SLICE_COLS * 2);
  unsigned short* O    = (unsigned short*)alloc((size_t)2 * N_NODES * DH * 2);
  float* S       = (float*)alloc((size_t)N_NODES * KC * 4);
  int*   ecol    = (int*)alloc((size_t)NE * 4);
  float* eval    = (float*)alloc((size_t)NE * 4);
  int*   row_ptr = (int*)alloc((size_t)(N_NODES + 1) * 4);
  int*   cursor  = (int*)alloc((size_t)N_NODES * 4);
  int*   counts  = (int*)alloc((size_t)N_NODES * 4);
  float* exptot  = (float*)alloc((size_t)DH * 4);   // contiguous zero region:
  float* augtot  = (float*)alloc((size_t)DH * 4);   //   exptot | augtot | scal
  float* scal    = (float*)alloc(64 * 4);
  if (off > ws_size) return;  // workspace too small: fail loudly, no OOB

  hipMemsetAsync(counts, 0, (size_t)N_NODES * 4, stream);
  hipMemsetAsync(exptot, 0, (size_t)DH * 4 * 2 + 64 * 4, stream);

  // W1 -> bf16 (tiny)
  k_cvt_pad<<<128, 256, 0, stream>>>(W1, Wbf, DH, N_FEAT, DH, KPAD);

  // CSR build
  k_count<<<(NE + 255) / 256, 256, 0, stream>>>(grow, counts);
  k_scan<<<1, 1024, 0, stream>>>(counts, row_ptr, cursor);
  k_scatter<<<(NE + 255) / 256, 256, 0, stream>>>(grow, gcol, gnv, cursor, ecol, eval);

  // fused-conversion GEMM over both matrices -> slice-major XWs
  k_gemm_fused<<<M2 / 128, 512, 0, stream>>>(features, augf, Wbf, XWs);

  // XCD-sliced SpMM (+bias+selu) -> O bf16
  k_spmm_slice<<<SPMM_BLOCKS, 256, 0, stream>>>(row_ptr, ecol, eval, XWs, b1, O);

  // epilogue: S softmax + global partials
  k_post<<<SPMM_BLOCKS, 256, 0, stream>>>(O, Wt, bt, S, exptot, augtot,
                                          scal + 18, scal + 0);

  // graph stats on assignments
  k_edge<<<512, 256, 0, stream>>>(grow, gcol, gvals, S, scal + 2, scal + 1);

  // final scalar
  k_final<<<1, 256, 0, stream>>>(exptot, augtot, scal, (float*)d_out);
}